// Round 6
// baseline (267.501 us; speedup 1.0000x reference)
//
#include <hip/hip_runtime.h>

#define HH 384
#define WW 384
#define OUTD 370
#define TILE 32
#define NTILE 12
#define LS 47            // image LDS tile extent and stride (odd -> mixed-parity banks)
#define TMLD 39          // tmp_T stride (transposed [col][row]), odd -> 2-way max
#define NPIX (4 * OUTD * OUTD)
#define NSHIFT 99

#define G0 0.32465246735834974f   // exp(-9/8)
#define G1 0.6065306597126334f    // exp(-4/8)
#define G2 0.8824969025845955f    // exp(-1/8)
#define KS 0.039788735772973836f  // 1/(8*pi)

typedef float v2f __attribute__((ext_vector_type(2)));

// 7-tap on packed pairs -> v_pk_add/v_pk_fma (gfx950 packed FP32)
__device__ __forceinline__ v2f tap7p(const v2f* P)
{
    return G0 * (P[0] + P[6]) + G1 * (P[1] + P[5]) + G2 * (P[2] + P[4]) + P[3];
}

__device__ __forceinline__ void load_img_tile(const float* __restrict__ img,
                                              int oy0, int ox0, float* L, int tid)
{
    for (int i = tid; i < LS * LS; i += 256) {
        int r = i / LS, c = i - r * LS;
        int gr = oy0 + r; if (gr >= HH) gr -= HH;   // exact circular wrap
        int gc = ox0 + c; if (gc >= WW) gc -= WW;
        L[i] = img[gr * WW + gc];
    }
}

__device__ __forceinline__ void shift_of(int s, int& sx, int& sy)
{
    int t = (s < 55) ? s : s + 1;    // skip (0,0)
    sx = t / 10 - 5;
    sy = t - (t / 10) * 10 - 5;
}

// center window preload: cA[j] = (Lc[j], Lc[j+4]) -- loop-invariant, registers
__device__ __forceinline__ void preload_c(const float* __restrict__ Lb,
                                          int r, int c0, v2f* cA)
{
    const float* Lc = &Lb[(r + 4) * LS + c0 + 4];
#pragma unroll
    for (int j = 0; j < 10; ++j) { cA[j].x = Lc[j]; cA[j].y = Lc[j + 4]; }
}

// horizontal 7-tap over inline diff^2; unit: row r, col-octet c0; outputs paired (k,k+4).
// Shifted reads: ds_read2_b32 (j, j+4); lane residue 15r+8oct+j -> mixed parity (no conflict).
__device__ __forceinline__ void horiz_pk(const float* __restrict__ Lb,
                                         const v2f* __restrict__ cA,
                                         float* __restrict__ tb,
                                         int r, int c0, int soff)
{
    const float* Ls = &Lb[r * LS + c0 + soff];
    v2f S[10];
#pragma unroll
    for (int j = 0; j < 10; ++j) {
        v2f p; p.x = Ls[j]; p.y = Ls[j + 4];
        v2f d = cA[j] - p;
        S[j] = d * d;
    }
    float* o = &tb[c0 * TMLD + r];
#pragma unroll
    for (int k = 0; k < 4; ++k) {
        v2f t = tap7p(S + k);
        o[k * TMLD] = t.x;              // merges into ds_write2_b32 (0, 4*TMLD)
        o[(k + 4) * TMLD] = t.y;
    }
}

// Stage 2: per (tile, batch, image, shift-half): partial vsum (4 cardinals) and minD
// over ~50 shifts; merged across halves via atomicAdd / atomicMin (D >= 0).
extern "C" __global__ void __launch_bounds__(256, 6)
mind_stage2(const float* __restrict__ pred, const float* __restrict__ gt,
            float* __restrict__ ws)
{
    __shared__ float L[LS * LS];
    __shared__ float tT[2][TILE * TMLD];
    const int tid = threadIdx.x;
    const int b = blockIdx.y;
    const int img = blockIdx.z >> 1, half = blockIdx.z & 1;
    const int oy0 = ((int)blockIdx.x / NTILE) * TILE;
    const int ox0 = ((int)blockIdx.x % NTILE) * TILE;
    const float* src = (img ? gt : pred) + (size_t)b * HH * WW;

    load_img_tile(src, oy0, ox0, L, tid);
    const int hr = tid >> 2, hc0 = (tid & 3) << 3;   // horiz unit (tid<152)
    const int x = tid & 31, ry0 = (tid >> 5) * 8;    // vert unit (tid<128): col x, 8 rows
    __syncthreads();

    v2f cA[10];
    if (tid < 152) preload_c(L, hr, hc0, cA);

    v2f dmin2[4], vsum2[4];
#pragma unroll
    for (int k = 0; k < 4; ++k) { dmin2[k] = (v2f)(1e30f); vsum2[k] = (v2f)(0.f); }

    const int s_beg = half * 50;
    const int s_end = half ? NSHIFT : 50;
    for (int s = s_beg; s < s_end; ++s) {
        int sx, sy; shift_of(s, sx, sy);
        int soff = (4 - sy) * LS + (4 - sx);
        if (tid < 152) horiz_pk(L, cA, tT[s & 1], hr, hc0, soff);
        __syncthreads();
        if (tid < 128) {
            const float* t = &tT[s & 1][x * TMLD + ry0];
            v2f W[10];
#pragma unroll
            for (int j = 0; j < 10; ++j) { W[j].x = t[j]; W[j].y = t[j + 4]; }
            const bool card = (sx * sx + sy * sy) == 1;
#pragma unroll
            for (int k = 0; k < 4; ++k) {
                v2f D2 = KS * tap7p(W + k);          // rows (ry0+k, ry0+k+4)
                dmin2[k].x = fminf(dmin2[k].x, D2.x);
                dmin2[k].y = fminf(dmin2[k].y, D2.y);
                if (card) vsum2[k] += D2;
            }
        }
    }

    if (tid < 128) {
        float* V = ws + (size_t)img * NPIX;
        float* M = ws + (size_t)(2 + img) * NPIX;
        const int ox = ox0 + x;
#pragma unroll
        for (int k = 0; k < 4; ++k) {
#pragma unroll
            for (int h = 0; h < 2; ++h) {
                int oy = oy0 + ry0 + k + 4 * h;
                float vs = h ? vsum2[k].y : vsum2[k].x;
                float dm = h ? dmin2[k].y : dmin2[k].x;
                if (oy < OUTD && ox < OUTD) {
                    size_t idx = ((size_t)b * OUTD + oy) * OUTD + ox;
                    atomicAdd(&V[idx], vs);
                    atomicMin((unsigned int*)&M[idx], __float_as_uint(dm));
                }
            }
        }
    }
}

// Stage 3: per (tile, batch, shift-quarter): recompute D for both images,
// accumulate |exp((m-D)/V)p - (...)g|, reduce, atomicAdd scaled mean.
extern "C" __global__ void __launch_bounds__(256, 5)
mind_stage3(const float* __restrict__ pred, const float* __restrict__ gt,
            const float* __restrict__ ws, float* __restrict__ out)
{
    __shared__ float LP[LS * LS];
    __shared__ float LG[LS * LS];
    __shared__ float tTP[TILE * TMLD];
    __shared__ float tTG[TILE * TMLD];
    __shared__ float wred[4];
    const int tid = threadIdx.x;
    const int b = blockIdx.y, q = blockIdx.z;        // q = shift quarter
    const int oy0 = ((int)blockIdx.x / NTILE) * TILE;
    const int ox0 = ((int)blockIdx.x % NTILE) * TILE;

    load_img_tile(pred + (size_t)b * HH * WW, oy0, ox0, LP, tid);
    load_img_tile(gt   + (size_t)b * HH * WW, oy0, ox0, LG, tid);

    // combined horiz space: P units 0..151 and G units 0..151; pass A = tid (P:0..151,
    // G:152..255 -> units 0..103), pass B = tid<48 -> G units 104..151
    const bool gA = tid >= 152;
    const int uA = tid - (gA ? 152 : 0);
    const int rA = uA >> 2, cA0 = (uA & 3) << 3;
    const float* LbA = gA ? LG : LP;
    float* tbA = gA ? tTG : tTP;
    const bool hasB = tid < 48;
    const int uB = tid + 104;
    const int rB = uB >> 2, cB0 = (uB & 3) << 3;

    const int x = tid & 31, ry0 = (tid >> 5) * 4;    // vert: col x, 4 rows, both images

    const float* Vw = ws;
    const float* Mw = ws + (size_t)2 * NPIX;
    float rvp[4], rvg[4], mp[4], mg[4];
    bool valid[4];
#pragma unroll
    for (int k = 0; k < 4; ++k) {
        int oy = oy0 + ry0 + k, ox = ox0 + x;
        valid[k] = (oy < OUTD) && (ox < OUTD);
        if (valid[k]) {
            size_t idx = ((size_t)b * OUTD + oy) * OUTD + ox;
            rvp[k] = 1.0f / (0.25f * Vw[idx] + 1e-5f);          mp[k] = Mw[idx];
            rvg[k] = 1.0f / (0.25f * Vw[NPIX + idx] + 1e-5f);   mg[k] = Mw[NPIX + idx];
        } else {
            rvp[k] = 0.f; mp[k] = 0.f; rvg[k] = 0.f; mg[k] = 0.f;
        }
    }
    __syncthreads();

    v2f cWA[10], cWB[10];
    preload_c(LbA, rA, cA0, cWA);
    if (hasB) preload_c(LG, rB, cB0, cWB);

    const int s_beg = q * 25;
    const int s_end = (q == 3) ? NSHIFT : (s_beg + 25);
    float acc = 0.f;

    for (int s = s_beg; s < s_end; ++s) {
        int sx, sy; shift_of(s, sx, sy);
        int soff = (4 - sy) * LS + (4 - sx);
        horiz_pk(LbA, cWA, tbA, rA, cA0, soff);
        if (hasB) horiz_pk(LG, cWB, tTG, rB, cB0, soff);
        __syncthreads();                  // tTP/tTG ready
        float Dp[4], Dg[4];
        {
            const float* t = &tTP[x * TMLD + ry0];
            v2f W[8];
#pragma unroll
            for (int j = 0; j < 8; ++j) { W[j].x = t[j]; W[j].y = t[j + 2]; }
            v2f D0 = KS * tap7p(W);       // rows (ry0, ry0+2)
            v2f D1 = KS * tap7p(W + 1);   // rows (ry0+1, ry0+3)
            Dp[0] = D0.x; Dp[1] = D1.x; Dp[2] = D0.y; Dp[3] = D1.y;
        }
        {
            const float* t = &tTG[x * TMLD + ry0];
            v2f W[8];
#pragma unroll
            for (int j = 0; j < 8; ++j) { W[j].x = t[j]; W[j].y = t[j + 2]; }
            v2f D0 = KS * tap7p(W);
            v2f D1 = KS * tap7p(W + 1);
            Dg[0] = D0.x; Dg[1] = D1.x; Dg[2] = D0.y; Dg[3] = D1.y;
        }
#pragma unroll
        for (int k = 0; k < 4; ++k) {
            if (valid[k]) {
                float ep = __expf((mp[k] - Dp[k]) * rvp[k]);
                float eg = __expf((mg[k] - Dg[k]) * rvg[k]);
                acc += fabsf(ep - eg);
            }
        }
        __syncthreads();                  // vert done before next horiz overwrites
    }

#pragma unroll
    for (int off = 32; off > 0; off >>= 1) acc += __shfl_down(acc, off, 64);
    const int lane = tid & 63, wv = tid >> 6;
    if (lane == 0) wred[wv] = acc;
    __syncthreads();
    if (tid == 0) {
        const float SC = (float)(1.0 / 54212400.0);  // 1/(4*370*370*99)
        atomicAdd(out, (wred[0] + wred[1] + wred[2] + wred[3]) * SC);
    }
}

extern "C" void kernel_launch(void* const* d_in, const int* in_sizes, int n_in,
                              void* d_out, int out_size, void* d_ws, size_t ws_size,
                              hipStream_t stream)
{
    (void)in_sizes; (void)n_in; (void)out_size; (void)ws_size;
    const float* pred = (const float*)d_in[0];
    const float* gt   = (const float*)d_in[1];
    float* out = (float*)d_out;
    float* ws  = (float*)d_ws;

    // V planes (2 images) init 0 for atomicAdd; M planes init 0x7F7F7F7F = 3.39e38
    // sentinel for atomicMin on positive-float bits.
    hipMemsetAsync(ws, 0, (size_t)2 * NPIX * sizeof(float), stream);
    hipMemsetAsync((char*)ws + (size_t)2 * NPIX * sizeof(float), 0x7F,
                   (size_t)2 * NPIX * sizeof(float), stream);
    hipMemsetAsync(d_out, 0, sizeof(float), stream);

    dim3 g2(NTILE * NTILE, 4, 4);   // z: image(2) x shift-half(2)
    mind_stage2<<<g2, 256, 0, stream>>>(pred, gt, ws);
    dim3 g3(NTILE * NTILE, 4, 4);   // z: shift-quarter
    mind_stage3<<<g3, 256, 0, stream>>>(pred, gt, ws, out);
}

// Round 7
// 266.154 us; speedup vs baseline: 1.0051x; 1.0051x over previous
//
#include <hip/hip_runtime.h>

#define HH 384
#define WW 384
#define OUTD 370
#define TILE 32
#define NTILE 12
#define LS 47            // image LDS tile extent and stride (odd -> mixed-parity banks)
#define TMLD 39          // tmp_T stride (transposed [col][row]), odd -> 2-way max (free)
#define TTSZ (TILE * TMLD)
#define NPIX (4 * OUTD * OUTD)
#define NSHIFT 99

#define G0 0.32465246735834974f   // exp(-9/8)
#define G1 0.6065306597126334f    // exp(-4/8)
#define G2 0.8824969025845955f    // exp(-1/8)
#define KS 0.039788735772973836f  // 1/(8*pi)

__device__ __forceinline__ void load_img_tile(const float* __restrict__ img,
                                              int oy0, int ox0, float* L, int tid)
{
    int r = tid / LS, c = tid - r * LS;           // one div at entry, then increments
    for (int i = tid; i < LS * LS; i += 256) {
        int gr = oy0 + r; if (gr >= HH) gr -= HH; // exact circular wrap
        int gc = ox0 + c; if (gc >= WW) gc -= WW;
        L[i] = img[gr * WW + gc];
        c += 256 - 5 * LS;                        // 256 = 5*47 + 21
        r += 5;
        if (c >= LS) { c -= LS; ++r; }
        if (c < 0)   { c += LS; --r; }            // (unreachable, keeps compiler honest)
    }
}

__device__ __forceinline__ void shift_of(int s, int& sx, int& sy)
{
    int t = (s < 55) ? s : s + 1;    // skip (0,0)
    sx = t / 10 - 5;
    sy = t - (t / 10) * 10 - 5;
}

__device__ __forceinline__ float tap7(const float* v)
{
    return fmaf(G0, v[0] + v[6],
           fmaf(G1, v[1] + v[5],
           fmaf(G2, v[2] + v[4], v[3])));
}

// horizontal 7-tap over diff^2 formed INLINE from L (no sq buffer):
// center window cA loop-invariant (registers); shifted window = 7x ds_read2 (contiguous).
// 8 outputs written transposed into tmp_T[col][row].
__device__ __forceinline__ void horiz8(const float* __restrict__ Lb,
                                       const float* __restrict__ cA,
                                       float* __restrict__ tb,
                                       int r, int c0, int sx, int sy)
{
    const float* Ls = &Lb[(r + 4 - sy) * LS + (c0 + 4 - sx)];
    float v[14];
#pragma unroll
    for (int t = 0; t < 14; ++t) { float d = cA[t] - Ls[t]; v[t] = d * d; }
    float* o = &tb[c0 * TMLD + r];
#pragma unroll
    for (int k = 0; k < 8; ++k) o[k * TMLD] = tap7(v + k);
}

// vertical 7-tap from transposed tmp: consecutive reads -> ds_read2
__device__ __forceinline__ void vert4(const float* __restrict__ tT, int x, int ry0, float* D)
{
    const float* t = &tT[x * TMLD + ry0];
    float w[10];
#pragma unroll
    for (int j = 0; j < 10; ++j) w[j] = t[j];
#pragma unroll
    for (int k = 0; k < 4; ++k) D[k] = KS * tap7(w + k);
}

// Stage 2: per (tile, batch, image): V = mean of 4 cardinal D + eps, minD over 99 shifts.
// TWO shifts per barrier via 4 tT buffers: pair p writes {2(p&1), 2(p&1)+1}; vert(pair p)
// completes before barrier(p+1), and horiz(pair p+2) reuses those buffers only after it.
extern "C" __global__ void __launch_bounds__(256, 5)
mind_stage2(const float* __restrict__ pred, const float* __restrict__ gt,
            float* __restrict__ ws)
{
    __shared__ float L[LS * LS];
    __shared__ float tT[4][TTSZ];
    const int tid = threadIdx.x;
    const int b = blockIdx.y, z = blockIdx.z;
    const int oy0 = ((int)blockIdx.x / NTILE) * TILE;
    const int ox0 = ((int)blockIdx.x % NTILE) * TILE;
    const float* img = (z ? gt : pred) + (size_t)b * HH * WW;

    load_img_tile(img, oy0, ox0, L, tid);
    const int hr = tid >> 2, hc0 = (tid & 3) << 3;   // horiz unit (tid<152)
    const int x = tid & 31, ry0 = (tid >> 5) * 8;    // vert unit (tid<128): col x, 8 rows
    __syncthreads();

    float cA[14];
    if (tid < 152) {
        const float* p = &L[(hr + 4) * LS + hc0 + 4];
#pragma unroll
        for (int t = 0; t < 14; ++t) cA[t] = p[t];
    }

    float dmin[8], vsum[8];
#pragma unroll
    for (int k = 0; k < 8; ++k) { dmin[k] = 1e30f; vsum[k] = 0.f; }

    for (int sp = 0; sp < NSHIFT; sp += 2) {
        const int base = ((sp >> 1) & 1) << 1;       // alternating buffer pair {0,1}/{2,3}
        int sx0, sy0, sx1 = 0, sy1 = 0;
        shift_of(sp, sx0, sy0);
        const bool has1 = (sp + 1) < NSHIFT;
        if (has1) shift_of(sp + 1, sx1, sy1);
        if (tid < 152) {
            horiz8(L, cA, tT[base], hr, hc0, sx0, sy0);
            if (has1) horiz8(L, cA, tT[base + 1], hr, hc0, sx1, sy1);
        }
        __syncthreads();
        if (tid < 128) {
#pragma unroll
            for (int h = 0; h < 2; ++h) {
                if (h && !has1) break;
                const float* t = &tT[base + h][x * TMLD + ry0];
                float w[14];
#pragma unroll
                for (int j = 0; j < 14; ++j) w[j] = t[j];
                const int sx = h ? sx1 : sx0, sy = h ? sy1 : sy0;
                const bool card = (sx * sx + sy * sy) == 1;
#pragma unroll
                for (int k = 0; k < 8; ++k) {
                    float D = KS * tap7(w + k);
                    dmin[k] = fminf(dmin[k], D);
                    if (card) vsum[k] += D;
                }
            }
        }
    }

    if (tid < 128) {
        float* V = ws + (size_t)z * NPIX;
        float* M = ws + (size_t)(2 + z) * NPIX;
#pragma unroll
        for (int k = 0; k < 8; ++k) {
            int oy = oy0 + ry0 + k, ox = ox0 + x;
            if (oy < OUTD && ox < OUTD) {
                size_t idx = ((size_t)b * OUTD + oy) * OUTD + ox;
                V[idx] = vsum[k] * 0.25f + 1e-5f;
                M[idx] = dmin[k];
            }
        }
    }
}

// Stage 3: recompute D per shift for both images, accumulate |exp - exp|, atomicAdd mean.
// ONE barrier per shift via double-buffered tTP/tTG (vert(s) precedes barrier(s+1),
// horiz(s+2) follows it -> WAR-safe). Horiz: combined 304-unit space, branchless ptr-select.
extern "C" __global__ void __launch_bounds__(256, 4)
mind_stage3(const float* __restrict__ pred, const float* __restrict__ gt,
            const float* __restrict__ ws, float* __restrict__ out)
{
    __shared__ float LP[LS * LS];
    __shared__ float LG[LS * LS];
    __shared__ float tTP[2][TTSZ];
    __shared__ float tTG[2][TTSZ];
    __shared__ float wred[4];
    const int tid = threadIdx.x;
    const int b = blockIdx.y, zh = blockIdx.z;       // zh = shift half
    const int oy0 = ((int)blockIdx.x / NTILE) * TILE;
    const int ox0 = ((int)blockIdx.x % NTILE) * TILE;

    load_img_tile(pred + (size_t)b * HH * WW, oy0, ox0, LP, tid);
    load_img_tile(gt   + (size_t)b * HH * WW, oy0, ox0, LG, tid);

    // combined horiz unit space: pass A = all 256 (P:0..151, G:0..103), pass B = tid<48 (G:104..151)
    const bool gA = tid >= 152;
    const int uA = tid - (gA ? 152 : 0);
    const int rA = uA >> 2, cA0 = (uA & 3) << 3;
    const float* LbA = gA ? LG : LP;
    float* tbA = gA ? tTG[0] : tTP[0];
    const bool hasB = tid < 48;
    const int uB = tid + 104;
    const int rB = uB >> 2, cB0 = (uB & 3) << 3;

    const int x = tid & 31, ry0 = (tid >> 5) * 4;    // vert: col x, 4 rows, both images

    const float* Vp = ws;
    const float* Vg = ws + (size_t)NPIX;
    const float* Mp = ws + (size_t)2 * NPIX;
    const float* Mg = ws + (size_t)3 * NPIX;
    float rvp[4], rvg[4], mp[4], mg[4];
    bool valid[4];
#pragma unroll
    for (int k = 0; k < 4; ++k) {
        int oy = oy0 + ry0 + k, ox = ox0 + x;
        valid[k] = (oy < OUTD) && (ox < OUTD);
        if (valid[k]) {
            size_t idx = ((size_t)b * OUTD + oy) * OUTD + ox;
            rvp[k] = 1.0f / Vp[idx]; mp[k] = Mp[idx];
            rvg[k] = 1.0f / Vg[idx]; mg[k] = Mg[idx];
        } else {
            rvp[k] = 0.f; mp[k] = 0.f; rvg[k] = 0.f; mg[k] = 0.f;
        }
    }
    __syncthreads();

    float cWA[14], cWB[14];
    {
        const float* p = &LbA[(rA + 4) * LS + cA0 + 4];
#pragma unroll
        for (int t = 0; t < 14; ++t) cWA[t] = p[t];
    }
    if (hasB) {
        const float* p = &LG[(rB + 4) * LS + cB0 + 4];
#pragma unroll
        for (int t = 0; t < 14; ++t) cWB[t] = p[t];
    }

    const int s_beg = zh * 50;
    const int s_end = zh ? NSHIFT : 50;
    float acc = 0.f;

    for (int s = s_beg; s < s_end; ++s) {
        const int buf = s & 1;
        int sx, sy; shift_of(s, sx, sy);
        horiz8(LbA, cWA, tbA + buf * TTSZ, rA, cA0, sx, sy);
        if (hasB) horiz8(LG, cWB, tTG[buf], rB, cB0, sx, sy);
        __syncthreads();                  // tTP/tTG[buf] ready
        float Dp[4], Dg[4];
        vert4(tTP[buf], x, ry0, Dp);
        vert4(tTG[buf], x, ry0, Dg);
#pragma unroll
        for (int k = 0; k < 4; ++k) {
            if (valid[k]) {
                float ep = __expf((mp[k] - Dp[k]) * rvp[k]);
                float eg = __expf((mg[k] - Dg[k]) * rvg[k]);
                acc += fabsf(ep - eg);
            }
        }
        // no second barrier: next horiz targets the other buffer; reuse of THIS buffer
        // happens only after the next iteration's barrier, which orders it after vert(s).
    }

#pragma unroll
    for (int off = 32; off > 0; off >>= 1) acc += __shfl_down(acc, off, 64);
    const int lane = tid & 63, wv = tid >> 6;
    if (lane == 0) wred[wv] = acc;
    __syncthreads();
    if (tid == 0) {
        const float SC = (float)(1.0 / 54212400.0);  // 1/(4*370*370*99)
        atomicAdd(out, (wred[0] + wred[1] + wred[2] + wred[3]) * SC);
    }
}

extern "C" void kernel_launch(void* const* d_in, const int* in_sizes, int n_in,
                              void* d_out, int out_size, void* d_ws, size_t ws_size,
                              hipStream_t stream)
{
    (void)in_sizes; (void)n_in; (void)out_size; (void)ws_size;
    const float* pred = (const float*)d_in[0];
    const float* gt   = (const float*)d_in[1];
    float* out = (float*)d_out;
    float* ws  = (float*)d_ws;

    hipMemsetAsync(d_out, 0, sizeof(float), stream);

    dim3 g2(NTILE * NTILE, 4, 2);   // z: image
    mind_stage2<<<g2, 256, 0, stream>>>(pred, gt, ws);
    dim3 g3(NTILE * NTILE, 4, 2);   // z: shift half
    mind_stage3<<<g3, 256, 0, stream>>>(pred, gt, ws, out);
}

// Round 8
// 241.909 us; speedup vs baseline: 1.1058x; 1.1002x over previous
//
#include <hip/hip_runtime.h>

#define HH 384
#define WW 384
#define OUTD 370
#define NPIX (4 * OUTD * OUTD)
#define NSHIFT 99

// ---- stage2 tile: 48 wide x 32 tall ----
#define S2W 48
#define S2H 32
#define LSW 63           // L width/stride for 48-wide tile (odd -> mixed-parity banks)
#define LSH 47           // L rows (32 + 6 conv + 9 shift span)
#define NXT2 8           // ceil(370/48)
#define NYT2 12          // ceil(370/32)
#define TMLD 39          // tmp_T stride ([col][row], 38 rows + 1 pad, odd)
#define TTSZ2 (S2W * TMLD)

// ---- stage3 tile: 32x32 (exact R5) ----
#define TILE 32
#define NTILE 12
#define LS 47
#define TTSZ (TILE * TMLD)

#define G0 0.32465246735834974f   // exp(-9/8)
#define G1 0.6065306597126334f    // exp(-4/8)
#define G2 0.8824969025845955f    // exp(-1/8)
#define KS 0.039788735772973836f  // 1/(8*pi)

__device__ __forceinline__ float tap7(const float* v)
{
    return fmaf(G0, v[0] + v[6],
           fmaf(G1, v[1] + v[5],
           fmaf(G2, v[2] + v[4], v[3])));
}

__device__ __forceinline__ void shift_of(int s, int& sx, int& sy)
{
    int t = (s < 55) ? s : s + 1;    // skip (0,0)
    sx = t / 10 - 5;
    sy = t - (t / 10) * 10 - 5;
}

// generic circular tile load, W x Hrows, stride W
template<int W, int Hrows>
__device__ __forceinline__ void load_tile(const float* __restrict__ img,
                                          int oy0, int ox0, float* L, int tid)
{
    for (int i = tid; i < W * Hrows; i += 256) {
        int r = i / W, c = i - r * W;
        int gr = oy0 + r; if (gr >= HH) gr -= HH;
        int gc = ox0 + c; if (gc >= WW) gc -= WW;
        L[i] = img[gr * WW + gc];
    }
}

// horizontal 7-tap over inline diff^2; 8 outputs -> transposed tmp
template<int LW>
__device__ __forceinline__ void horiz8(const float* __restrict__ Lb,
                                       const float* __restrict__ cA,
                                       float* __restrict__ tb,
                                       int r, int c0, int sx, int sy)
{
    const float* Ls = &Lb[(r + 4 - sy) * LW + (c0 + 4 - sx)];
    float v[14];
#pragma unroll
    for (int t = 0; t < 14; ++t) { float d = cA[t] - Ls[t]; v[t] = d * d; }
    float* o = &tb[c0 * TMLD + r];
#pragma unroll
    for (int k = 0; k < 8; ++k) o[k * TMLD] = tap7(v + k);
}

__device__ __forceinline__ void vert4(const float* __restrict__ tT, int x, int ry0, float* D)
{
    const float* t = &tT[x * TMLD + ry0];
    float w[10];
#pragma unroll
    for (int j = 0; j < 10; ++j) w[j] = t[j];
#pragma unroll
    for (int k = 0; k < 4; ++k) D[k] = KS * tap7(w + k);
}

// Stage 2: 48x32 tile per (tile,b,image). Balanced partition: horiz 228/256 units,
// vert 192 threads x 8-row strips. Double-buffered tT -> 1 barrier/shift.
// Grid 768 = exactly 3 blocks/CU; LDS 26.9KB -> 5 fit.
extern "C" __global__ void __launch_bounds__(256, 5)
mind_stage2(const float* __restrict__ pred, const float* __restrict__ gt,
            float* __restrict__ ws)
{
    __shared__ float L[LSW * LSH];
    __shared__ float tT[2][TTSZ2];
    const int tid = threadIdx.x;
    const int b = blockIdx.y, z = blockIdx.z;
    const int oy0 = ((int)blockIdx.x / NXT2) * S2H;
    const int ox0 = ((int)blockIdx.x % NXT2) * S2W;
    const float* img = (z ? gt : pred) + (size_t)b * HH * WW;

    load_tile<LSW, LSH>(img, oy0, ox0, L, tid);
    // horiz: 228 units = 38 rows x 6 col-octets
    const bool hasH = tid < 228;
    const int hr = tid / 6, hc0 = (tid - hr * 6) * 8;
    // vert: 192 units = 48 cols x 4 strips of 8 rows
    const bool hasV = tid < 192;
    const int vx = tid % 48, vy0 = (tid / 48) * 8;
    __syncthreads();

    float cA[14];
    if (hasH) {
        const float* p = &L[(hr + 4) * LSW + hc0 + 4];
#pragma unroll
        for (int t = 0; t < 14; ++t) cA[t] = p[t];
    }

    float dmin[8], vsum[8];
#pragma unroll
    for (int k = 0; k < 8; ++k) { dmin[k] = 1e30f; vsum[k] = 0.f; }

    for (int s = 0; s < NSHIFT; ++s) {
        int sx, sy; shift_of(s, sx, sy);
        if (hasH) horiz8<LSW>(L, cA, tT[s & 1], hr, hc0, sx, sy);
        __syncthreads();   // tT[s&1] ready; alternation makes WAR with vert(s-1) safe
        if (hasV) {
            const float* t = &tT[s & 1][vx * TMLD + vy0];
            float w[14];
#pragma unroll
            for (int j = 0; j < 14; ++j) w[j] = t[j];
            const bool card = (sx * sx + sy * sy) == 1;
#pragma unroll
            for (int k = 0; k < 8; ++k) {
                float D = KS * tap7(w + k);
                dmin[k] = fminf(dmin[k], D);
                if (card) vsum[k] += D;
            }
        }
    }

    if (hasV) {
        float* V = ws + (size_t)z * NPIX;
        float* M = ws + (size_t)(2 + z) * NPIX;
        const int ox = ox0 + vx;
#pragma unroll
        for (int k = 0; k < 8; ++k) {
            int oy = oy0 + vy0 + k;
            if (oy < OUTD && ox < OUTD) {
                size_t idx = ((size_t)b * OUTD + oy) * OUTD + ox;
                V[idx] = vsum[k] * 0.25f + 1e-5f;
                M[idx] = dmin[k];
            }
        }
    }
}

// Stage 3: EXACT R5 structure (best measured): 32x32 tile, both images, 2 barriers/shift,
// LDS 27.7KB -> 5 blocks/CU >= grid's 4.5. All 256 threads active in horiz (A+B), vert, loss.
extern "C" __global__ void __launch_bounds__(256, 5)
mind_stage3(const float* __restrict__ pred, const float* __restrict__ gt,
            const float* __restrict__ ws, float* __restrict__ out)
{
    __shared__ float LP[LS * LS];
    __shared__ float LG[LS * LS];
    __shared__ float tTP[TTSZ];
    __shared__ float tTG[TTSZ];
    __shared__ float wred[4];
    const int tid = threadIdx.x;
    const int b = blockIdx.y, zh = blockIdx.z;       // zh = shift half
    const int oy0 = ((int)blockIdx.x / NTILE) * TILE;
    const int ox0 = ((int)blockIdx.x % NTILE) * TILE;

    load_tile<LS, LS>(pred + (size_t)b * HH * WW, oy0, ox0, LP, tid);
    load_tile<LS, LS>(gt   + (size_t)b * HH * WW, oy0, ox0, LG, tid);

    // combined horiz space: pass A = all 256 (P:0..151, G:0..103), pass B = tid<48 (G:104..151)
    const bool gA = tid >= 152;
    const int uA = tid - (gA ? 152 : 0);
    const int rA = uA >> 2, cA0 = (uA & 3) << 3;
    const float* LbA = gA ? LG : LP;
    float* tbA = gA ? tTG : tTP;
    const bool hasB = tid < 48;
    const int uB = tid + 104;
    const int rB = uB >> 2, cB0 = (uB & 3) << 3;

    const int x = tid & 31, ry0 = (tid >> 5) * 4;    // vert: col x, 4 rows, both images

    const float* Vp = ws;
    const float* Vg = ws + (size_t)NPIX;
    const float* Mp = ws + (size_t)2 * NPIX;
    const float* Mg = ws + (size_t)3 * NPIX;
    float rvp[4], rvg[4], mp[4], mg[4];
    bool valid[4];
#pragma unroll
    for (int k = 0; k < 4; ++k) {
        int oy = oy0 + ry0 + k, ox = ox0 + x;
        valid[k] = (oy < OUTD) && (ox < OUTD);
        if (valid[k]) {
            size_t idx = ((size_t)b * OUTD + oy) * OUTD + ox;
            rvp[k] = 1.0f / Vp[idx]; mp[k] = Mp[idx];
            rvg[k] = 1.0f / Vg[idx]; mg[k] = Mg[idx];
        } else {
            rvp[k] = 0.f; mp[k] = 0.f; rvg[k] = 0.f; mg[k] = 0.f;
        }
    }
    __syncthreads();

    float cWA[14], cWB[14];
    {
        const float* p = &LbA[(rA + 4) * LS + cA0 + 4];
#pragma unroll
        for (int t = 0; t < 14; ++t) cWA[t] = p[t];
    }
    if (hasB) {
        const float* p = &LG[(rB + 4) * LS + cB0 + 4];
#pragma unroll
        for (int t = 0; t < 14; ++t) cWB[t] = p[t];
    }

    const int s_beg = zh * 50;
    const int s_end = zh ? NSHIFT : 50;
    float acc = 0.f;

    for (int s = s_beg; s < s_end; ++s) {
        int sx, sy; shift_of(s, sx, sy);
        horiz8<LS>(LbA, cWA, tbA, rA, cA0, sx, sy);
        if (hasB) horiz8<LS>(LG, cWB, tTG, rB, cB0, sx, sy);
        __syncthreads();                  // tTP/tTG ready
        float Dp[4], Dg[4];
        vert4(tTP, x, ry0, Dp);
        vert4(tTG, x, ry0, Dg);
#pragma unroll
        for (int k = 0; k < 4; ++k) {
            if (valid[k]) {
                float ep = __expf((mp[k] - Dp[k]) * rvp[k]);
                float eg = __expf((mg[k] - Dg[k]) * rvg[k]);
                acc += fabsf(ep - eg);
            }
        }
        __syncthreads();                  // vert done before next horiz overwrites
    }

#pragma unroll
    for (int off = 32; off > 0; off >>= 1) acc += __shfl_down(acc, off, 64);
    const int lane = tid & 63, wv = tid >> 6;
    if (lane == 0) wred[wv] = acc;
    __syncthreads();
    if (tid == 0) {
        const float SC = (float)(1.0 / 54212400.0);  // 1/(4*370*370*99)
        atomicAdd(out, (wred[0] + wred[1] + wred[2] + wred[3]) * SC);
    }
}

extern "C" void kernel_launch(void* const* d_in, const int* in_sizes, int n_in,
                              void* d_out, int out_size, void* d_ws, size_t ws_size,
                              hipStream_t stream)
{
    (void)in_sizes; (void)n_in; (void)out_size; (void)ws_size;
    const float* pred = (const float*)d_in[0];
    const float* gt   = (const float*)d_in[1];
    float* out = (float*)d_out;
    float* ws  = (float*)d_ws;

    hipMemsetAsync(d_out, 0, sizeof(float), stream);

    dim3 g2(NXT2 * NYT2, 4, 2);     // 96 tiles x 4 batch x 2 images = 768 = 3/CU exact
    mind_stage2<<<g2, 256, 0, stream>>>(pred, gt, ws);
    dim3 g3(NTILE * NTILE, 4, 2);   // 144 tiles x 4 batch x 2 shift-halves
    mind_stage3<<<g3, 256, 0, stream>>>(pred, gt, ws, out);
}

// Round 9
// 239.716 us; speedup vs baseline: 1.1159x; 1.0091x over previous
//
#include <hip/hip_runtime.h>

#define HH 384
#define WW 384
#define OUTD 370
#define NPIX (4 * OUTD * OUTD)
#define NSHIFT 99

// ---- stage2 tile: 64 wide x 24 tall (all power-of-2 lane decodes) ----
#define S2W 64
#define S2H 24
#define LW2 79           // L stride = 64+15; 79 mod 32 = 15 -> read residue 15r+8c, 2-way
#define LH2 39           // L rows = 24+15
#define TM2 31           // tmp_T stride (30 rows + 1); 31 mod 32 = -1 -> 2-way
#define NXT2 6           // ceil(370/64)
#define NYT2 16          // ceil(370/24)
#define TTS2 (S2W * TM2)

// ---- stage3 tile: 32x32 (exact R5/R8 structure, measured best) ----
#define TILE 32
#define NTILE 12
#define LS 47
#define TMLD 39
#define TTSZ (TILE * TMLD)

#define G0 0.32465246735834974f   // exp(-9/8)
#define G1 0.6065306597126334f    // exp(-4/8)
#define G2 0.8824969025845955f    // exp(-1/8)
#define KS 0.039788735772973836f  // 1/(8*pi)

__device__ __forceinline__ float tap7(const float* v)
{
    return fmaf(G0, v[0] + v[6],
           fmaf(G1, v[1] + v[5],
           fmaf(G2, v[2] + v[4], v[3])));
}

__device__ __forceinline__ void shift_of(int s, int& sx, int& sy)
{
    int t = (s < 55) ? s : s + 1;    // skip (0,0)
    sx = t / 10 - 5;
    sy = t - (t / 10) * 10 - 5;
}

// generic circular tile load, W x Hrows, stride W
template<int W, int Hrows>
__device__ __forceinline__ void load_tile(const float* __restrict__ img,
                                          int oy0, int ox0, float* L, int tid)
{
    for (int i = tid; i < W * Hrows; i += 256) {
        int r = i / W, c = i - r * W;
        int gr = oy0 + r; if (gr >= HH) gr -= HH;
        int gc = ox0 + c; if (gc >= WW) gc -= WW;
        L[i] = img[gr * WW + gc];
    }
}

// horizontal 7-tap over inline diff^2; 8 outputs -> transposed tmp (stride TS)
template<int LW, int TS>
__device__ __forceinline__ void horiz8(const float* __restrict__ Lb,
                                       const float* __restrict__ cA,
                                       float* __restrict__ tb,
                                       int r, int c0, int sx, int sy)
{
    const float* Ls = &Lb[(r + 4 - sy) * LW + (c0 + 4 - sx)];
    float v[14];
#pragma unroll
    for (int t = 0; t < 14; ++t) { float d = cA[t] - Ls[t]; v[t] = d * d; }
    float* o = &tb[c0 * TS + r];
#pragma unroll
    for (int k = 0; k < 8; ++k) o[k * TS] = tap7(v + k);
}

__device__ __forceinline__ void vert4(const float* __restrict__ tT, int x, int ry0, float* D)
{
    const float* t = &tT[x * TMLD + ry0];
    float w[10];
#pragma unroll
    for (int j = 0; j < 10; ++j) w[j] = t[j];
#pragma unroll
    for (int k = 0; k < 4; ++k) D[k] = KS * tap7(w + k);
}

// Stage 2: 64x24 tile per (tile,b,image). horiz 240/256 units (exact 2-way banks);
// vert+loss 256/256 (64 cols x 4 strips of 6 rows). Double-buffered tT, 1 barrier/shift.
// Grid 768 = exactly 3 blocks/CU; LDS 28.2KB -> 5 fit.
extern "C" __global__ void __launch_bounds__(256, 5)
mind_stage2(const float* __restrict__ pred, const float* __restrict__ gt,
            float* __restrict__ ws)
{
    __shared__ float L[LW2 * LH2];
    __shared__ float tT[2][TTS2];
    const int tid = threadIdx.x;
    const int b = blockIdx.y, z = blockIdx.z;
    const int oy0 = ((int)blockIdx.x / NXT2) * S2H;
    const int ox0 = ((int)blockIdx.x % NXT2) * S2W;
    const float* img = (z ? gt : pred) + (size_t)b * HH * WW;

    load_tile<LW2, LH2>(img, oy0, ox0, L, tid);
    // horiz: 240 units = 30 rows x 8 col-octets, power-of-2 decode
    const bool hasH = tid < 240;
    const int hr = tid >> 3, hc0 = (tid & 7) << 3;
    // vert: 256 units = 64 cols x 4 strips of 6 rows
    const int vx = tid & 63, vy0 = (tid >> 6) * 6;
    __syncthreads();

    float cA[14];
    if (hasH) {
        const float* p = &L[(hr + 4) * LW2 + hc0 + 4];
#pragma unroll
        for (int t = 0; t < 14; ++t) cA[t] = p[t];
    }

    float dmin[6], vsum[6];
#pragma unroll
    for (int k = 0; k < 6; ++k) { dmin[k] = 1e30f; vsum[k] = 0.f; }

    for (int s = 0; s < NSHIFT; ++s) {
        int sx, sy; shift_of(s, sx, sy);
        if (hasH) horiz8<LW2, TM2>(L, cA, tT[s & 1], hr, hc0, sx, sy);
        __syncthreads();   // tT[s&1] ready; buffer alternation makes WAR with vert(s-1) safe
        {
            const float* t = &tT[s & 1][vx * TM2 + vy0];
            float w[12];
#pragma unroll
            for (int j = 0; j < 12; ++j) w[j] = t[j];
            const bool card = (sx * sx + sy * sy) == 1;
#pragma unroll
            for (int k = 0; k < 6; ++k) {
                float D = KS * tap7(w + k);
                dmin[k] = fminf(dmin[k], D);
                if (card) vsum[k] += D;
            }
        }
    }

    {
        float* V = ws + (size_t)z * NPIX;
        float* M = ws + (size_t)(2 + z) * NPIX;
        const int ox = ox0 + vx;
#pragma unroll
        for (int k = 0; k < 6; ++k) {
            int oy = oy0 + vy0 + k;
            if (oy < OUTD && ox < OUTD) {
                size_t idx = ((size_t)b * OUTD + oy) * OUTD + ox;
                V[idx] = vsum[k] * 0.25f + 1e-5f;
                M[idx] = dmin[k];
            }
        }
    }
}

// Stage 3: EXACT R8 structure (measured best): 32x32 tile, both images, 2 barriers/shift,
// LDS 27.7KB -> 5 blocks/CU >= grid's 4.5. All 256 threads active in horiz (A+B), vert, loss.
extern "C" __global__ void __launch_bounds__(256, 5)
mind_stage3(const float* __restrict__ pred, const float* __restrict__ gt,
            const float* __restrict__ ws, float* __restrict__ out)
{
    __shared__ float LP[LS * LS];
    __shared__ float LG[LS * LS];
    __shared__ float tTP[TTSZ];
    __shared__ float tTG[TTSZ];
    __shared__ float wred[4];
    const int tid = threadIdx.x;
    const int b = blockIdx.y, zh = blockIdx.z;       // zh = shift half
    const int oy0 = ((int)blockIdx.x / NTILE) * TILE;
    const int ox0 = ((int)blockIdx.x % NTILE) * TILE;

    load_tile<LS, LS>(pred + (size_t)b * HH * WW, oy0, ox0, LP, tid);
    load_tile<LS, LS>(gt   + (size_t)b * HH * WW, oy0, ox0, LG, tid);

    // combined horiz space: pass A = all 256 (P:0..151, G:0..103), pass B = tid<48 (G:104..151)
    const bool gA = tid >= 152;
    const int uA = tid - (gA ? 152 : 0);
    const int rA = uA >> 2, cA0 = (uA & 3) << 3;
    const float* LbA = gA ? LG : LP;
    float* tbA = gA ? tTG : tTP;
    const bool hasB = tid < 48;
    const int uB = tid + 104;
    const int rB = uB >> 2, cB0 = (uB & 3) << 3;

    const int x = tid & 31, ry0 = (tid >> 5) * 4;    // vert: col x, 4 rows, both images

    const float* Vp = ws;
    const float* Vg = ws + (size_t)NPIX;
    const float* Mp = ws + (size_t)2 * NPIX;
    const float* Mg = ws + (size_t)3 * NPIX;
    float rvp[4], rvg[4], mp[4], mg[4];
    bool valid[4];
#pragma unroll
    for (int k = 0; k < 4; ++k) {
        int oy = oy0 + ry0 + k, ox = ox0 + x;
        valid[k] = (oy < OUTD) && (ox < OUTD);
        if (valid[k]) {
            size_t idx = ((size_t)b * OUTD + oy) * OUTD + ox;
            rvp[k] = 1.0f / Vp[idx]; mp[k] = Mp[idx];
            rvg[k] = 1.0f / Vg[idx]; mg[k] = Mg[idx];
        } else {
            rvp[k] = 0.f; mp[k] = 0.f; rvg[k] = 0.f; mg[k] = 0.f;
        }
    }
    __syncthreads();

    float cWA[14], cWB[14];
    {
        const float* p = &LbA[(rA + 4) * LS + cA0 + 4];
#pragma unroll
        for (int t = 0; t < 14; ++t) cWA[t] = p[t];
    }
    if (hasB) {
        const float* p = &LG[(rB + 4) * LS + cB0 + 4];
#pragma unroll
        for (int t = 0; t < 14; ++t) cWB[t] = p[t];
    }

    const int s_beg = zh * 50;
    const int s_end = zh ? NSHIFT : 50;
    float acc = 0.f;

    for (int s = s_beg; s < s_end; ++s) {
        int sx, sy; shift_of(s, sx, sy);
        horiz8<LS, TMLD>(LbA, cWA, tbA, rA, cA0, sx, sy);
        if (hasB) horiz8<LS, TMLD>(LG, cWB, tTG, rB, cB0, sx, sy);
        __syncthreads();                  // tTP/tTG ready
        float Dp[4], Dg[4];
        vert4(tTP, x, ry0, Dp);
        vert4(tTG, x, ry0, Dg);
#pragma unroll
        for (int k = 0; k < 4; ++k) {
            if (valid[k]) {
                float ep = __expf((mp[k] - Dp[k]) * rvp[k]);
                float eg = __expf((mg[k] - Dg[k]) * rvg[k]);
                acc += fabsf(ep - eg);
            }
        }
        __syncthreads();                  // vert done before next horiz overwrites
    }

#pragma unroll
    for (int off = 32; off > 0; off >>= 1) acc += __shfl_down(acc, off, 64);
    const int lane = tid & 63, wv = tid >> 6;
    if (lane == 0) wred[wv] = acc;
    __syncthreads();
    if (tid == 0) {
        const float SC = (float)(1.0 / 54212400.0);  // 1/(4*370*370*99)
        atomicAdd(out, (wred[0] + wred[1] + wred[2] + wred[3]) * SC);
    }
}

extern "C" void kernel_launch(void* const* d_in, const int* in_sizes, int n_in,
                              void* d_out, int out_size, void* d_ws, size_t ws_size,
                              hipStream_t stream)
{
    (void)in_sizes; (void)n_in; (void)out_size; (void)ws_size;
    const float* pred = (const float*)d_in[0];
    const float* gt   = (const float*)d_in[1];
    float* out = (float*)d_out;
    float* ws  = (float*)d_ws;

    hipMemsetAsync(d_out, 0, sizeof(float), stream);

    dim3 g2(NXT2 * NYT2, 4, 2);     // 96 tiles x 4 batch x 2 images = 768 = 3/CU exact
    mind_stage2<<<g2, 256, 0, stream>>>(pred, gt, ws);
    dim3 g3(NTILE * NTILE, 4, 2);   // 144 tiles x 4 batch x 2 shift-halves
    mind_stage3<<<g3, 256, 0, stream>>>(pred, gt, ws, out);
}

// Round 10
// 234.415 us; speedup vs baseline: 1.1411x; 1.0226x over previous
//
#include <hip/hip_runtime.h>

#define HH 384
#define WW 384
#define OUTD 370
#define NPIX (4 * OUTD * OUTD)
#define NSHIFT 99

// ---- stage2 tile: 32 wide x 48 tall ----
// Bank rule (measured R5 vs R8/R9): LDS conflicts are PER 32-LANE PHASE; the
// (stride mod 32, unit-decode) pair must biject each half-wave onto the banks.
// Decode hr=tid>>2, hc0=(tid&3)<<3 with stride==15 (mod 32) is bijective; so is
// vert 23*vx (odd) and horiz-write 23*(hc0+k)+hr -> {0,24,16,8}+hr.
#define S2H 48
#define LS2 47           // L stride (47 mod 32 = 15)
#define LR2 63           // L rows = 48 + 6 conv + 9 shift span
#define TM2 55           // tmp_T stride = 54 rows + 1 (55 mod 32 = 23, odd)
#define NXT2 12          // ceil(370/32)
#define NYT2 8           // ceil(370/48)
#define TTS2 (32 * TM2)

// ---- stage3 tile: 32x32 (exact R8/R9 structure, measured best) ----
#define TILE 32
#define NTILE 12
#define LS 47
#define TMLD 39
#define TTSZ (TILE * TMLD)

#define G0 0.32465246735834974f   // exp(-9/8)
#define G1 0.6065306597126334f    // exp(-4/8)
#define G2 0.8824969025845955f    // exp(-1/8)
#define KS 0.039788735772973836f  // 1/(8*pi)

__device__ __forceinline__ float tap7(const float* v)
{
    return fmaf(G0, v[0] + v[6],
           fmaf(G1, v[1] + v[5],
           fmaf(G2, v[2] + v[4], v[3])));
}

__device__ __forceinline__ void shift_of(int s, int& sx, int& sy)
{
    int t = (s < 55) ? s : s + 1;    // skip (0,0)
    sx = t / 10 - 5;
    sy = t - (t / 10) * 10 - 5;
}

// generic circular tile load, W x Hrows, stride W
template<int W, int Hrows>
__device__ __forceinline__ void load_tile(const float* __restrict__ img,
                                          int oy0, int ox0, float* L, int tid)
{
    for (int i = tid; i < W * Hrows; i += 256) {
        int r = i / W, c = i - r * W;
        int gr = oy0 + r; if (gr >= HH) gr -= HH;
        int gc = ox0 + c; if (gc >= WW) gc -= WW;
        L[i] = img[gr * WW + gc];
    }
}

// horizontal 7-tap over inline diff^2; 8 outputs -> transposed tmp (stride TS)
template<int LW, int TS>
__device__ __forceinline__ void horiz8(const float* __restrict__ Lb,
                                       const float* __restrict__ cA,
                                       float* __restrict__ tb,
                                       int r, int c0, int sx, int sy)
{
    const float* Ls = &Lb[(r + 4 - sy) * LW + (c0 + 4 - sx)];
    float v[14];
#pragma unroll
    for (int t = 0; t < 14; ++t) { float d = cA[t] - Ls[t]; v[t] = d * d; }
    float* o = &tb[c0 * TS + r];
#pragma unroll
    for (int k = 0; k < 8; ++k) o[k * TS] = tap7(v + k);
}

__device__ __forceinline__ void vert4(const float* __restrict__ tT, int x, int ry0, float* D)
{
    const float* t = &tT[x * TMLD + ry0];
    float w[10];
#pragma unroll
    for (int j = 0; j < 10; ++j) w[j] = t[j];
#pragma unroll
    for (int k = 0; k < 4; ++k) D[k] = KS * tap7(w + k);
}

// Stage 2: 32x48 tile per (tile,b,image). horiz 216/256 units (per-phase bijective
// banks); vert+loss 256/256 (32 cols x 8 strips of 6 rows). Double-buffered tT,
// 1 barrier/shift. Grid 768 = exactly 3 blocks/CU, all resident (LDS 25.9KB -> 6 fit).
extern "C" __global__ void __launch_bounds__(256, 5)
mind_stage2(const float* __restrict__ pred, const float* __restrict__ gt,
            float* __restrict__ ws)
{
    __shared__ float L[LR2 * LS2];
    __shared__ float tT[2][TTS2];
    const int tid = threadIdx.x;
    const int b = blockIdx.y, z = blockIdx.z;
    const int oy0 = ((int)blockIdx.x / NXT2) * S2H;
    const int ox0 = ((int)blockIdx.x % NXT2) * TILE;
    const float* img = (z ? gt : pred) + (size_t)b * HH * WW;

    load_tile<LS2, LR2>(img, oy0, ox0, L, tid);
    // horiz: 216 units = 54 rows x 4 col-octets; R5-proven bijective decode
    const bool hasH = tid < 216;
    const int hr = tid >> 2, hc0 = (tid & 3) << 3;
    // vert: 256 units = 32 cols x 8 strips of 6 rows
    const int vx = tid & 31, vy0 = (tid >> 5) * 6;
    __syncthreads();

    float cA[14];
    if (hasH) {
        const float* p = &L[(hr + 4) * LS2 + hc0 + 4];
#pragma unroll
        for (int t = 0; t < 14; ++t) cA[t] = p[t];
    }

    float dmin[6], vsum[6];
#pragma unroll
    for (int k = 0; k < 6; ++k) { dmin[k] = 1e30f; vsum[k] = 0.f; }

    for (int s = 0; s < NSHIFT; ++s) {
        int sx, sy; shift_of(s, sx, sy);
        if (hasH) horiz8<LS2, TM2>(L, cA, tT[s & 1], hr, hc0, sx, sy);
        __syncthreads();   // tT[s&1] ready; buffer alternation makes WAR with vert(s-1) safe
        {
            const float* t = &tT[s & 1][vx * TM2 + vy0];
            float w[12];
#pragma unroll
            for (int j = 0; j < 12; ++j) w[j] = t[j];
            const bool card = (sx * sx + sy * sy) == 1;
#pragma unroll
            for (int k = 0; k < 6; ++k) {
                float D = KS * tap7(w + k);
                dmin[k] = fminf(dmin[k], D);
                if (card) vsum[k] += D;
            }
        }
    }

    {
        float* V = ws + (size_t)z * NPIX;
        float* M = ws + (size_t)(2 + z) * NPIX;
        const int ox = ox0 + vx;
#pragma unroll
        for (int k = 0; k < 6; ++k) {
            int oy = oy0 + vy0 + k;
            if (oy < OUTD && ox < OUTD) {
                size_t idx = ((size_t)b * OUTD + oy) * OUTD + ox;
                V[idx] = vsum[k] * 0.25f + 1e-5f;
                M[idx] = dmin[k];
            }
        }
    }
}

// Stage 3: EXACT R8/R9 structure (measured best): 32x32 tile, both images,
// 2 barriers/shift, LDS 27.7KB -> 5 blocks/CU >= grid's 4.5. All 256 threads
// active in horiz (A+B), vert, loss.
extern "C" __global__ void __launch_bounds__(256, 5)
mind_stage3(const float* __restrict__ pred, const float* __restrict__ gt,
            const float* __restrict__ ws, float* __restrict__ out)
{
    __shared__ float LP[LS * LS];
    __shared__ float LG[LS * LS];
    __shared__ float tTP[TTSZ];
    __shared__ float tTG[TTSZ];
    __shared__ float wred[4];
    const int tid = threadIdx.x;
    const int b = blockIdx.y, zh = blockIdx.z;       // zh = shift half
    const int oy0 = ((int)blockIdx.x / NTILE) * TILE;
    const int ox0 = ((int)blockIdx.x % NTILE) * TILE;

    load_tile<LS, LS>(pred + (size_t)b * HH * WW, oy0, ox0, LP, tid);
    load_tile<LS, LS>(gt   + (size_t)b * HH * WW, oy0, ox0, LG, tid);

    // combined horiz space: pass A = all 256 (P:0..151, G:0..103), pass B = tid<48 (G:104..151)
    const bool gA = tid >= 152;
    const int uA = tid - (gA ? 152 : 0);
    const int rA = uA >> 2, cA0 = (uA & 3) << 3;
    const float* LbA = gA ? LG : LP;
    float* tbA = gA ? tTG : tTP;
    const bool hasB = tid < 48;
    const int uB = tid + 104;
    const int rB = uB >> 2, cB0 = (uB & 3) << 3;

    const int x = tid & 31, ry0 = (tid >> 5) * 4;    // vert: col x, 4 rows, both images

    const float* Vp = ws;
    const float* Vg = ws + (size_t)NPIX;
    const float* Mp = ws + (size_t)2 * NPIX;
    const float* Mg = ws + (size_t)3 * NPIX;
    float rvp[4], rvg[4], mp[4], mg[4];
    bool valid[4];
#pragma unroll
    for (int k = 0; k < 4; ++k) {
        int oy = oy0 + ry0 + k, ox = ox0 + x;
        valid[k] = (oy < OUTD) && (ox < OUTD);
        if (valid[k]) {
            size_t idx = ((size_t)b * OUTD + oy) * OUTD + ox;
            rvp[k] = 1.0f / Vp[idx]; mp[k] = Mp[idx];
            rvg[k] = 1.0f / Vg[idx]; mg[k] = Mg[idx];
        } else {
            rvp[k] = 0.f; mp[k] = 0.f; rvg[k] = 0.f; mg[k] = 0.f;
        }
    }
    __syncthreads();

    float cWA[14], cWB[14];
    {
        const float* p = &LbA[(rA + 4) * LS + cA0 + 4];
#pragma unroll
        for (int t = 0; t < 14; ++t) cWA[t] = p[t];
    }
    if (hasB) {
        const float* p = &LG[(rB + 4) * LS + cB0 + 4];
#pragma unroll
        for (int t = 0; t < 14; ++t) cWB[t] = p[t];
    }

    const int s_beg = zh * 50;
    const int s_end = zh ? NSHIFT : 50;
    float acc = 0.f;

    for (int s = s_beg; s < s_end; ++s) {
        int sx, sy; shift_of(s, sx, sy);
        horiz8<LS, TMLD>(LbA, cWA, tbA, rA, cA0, sx, sy);
        if (hasB) horiz8<LS, TMLD>(LG, cWB, tTG, rB, cB0, sx, sy);
        __syncthreads();                  // tTP/tTG ready
        float Dp[4], Dg[4];
        vert4(tTP, x, ry0, Dp);
        vert4(tTG, x, ry0, Dg);
#pragma unroll
        for (int k = 0; k < 4; ++k) {
            if (valid[k]) {
                float ep = __expf((mp[k] - Dp[k]) * rvp[k]);
                float eg = __expf((mg[k] - Dg[k]) * rvg[k]);
                acc += fabsf(ep - eg);
            }
        }
        __syncthreads();                  // vert done before next horiz overwrites
    }

#pragma unroll
    for (int off = 32; off > 0; off >>= 1) acc += __shfl_down(acc, off, 64);
    const int lane = tid & 63, wv = tid >> 6;
    if (lane == 0) wred[wv] = acc;
    __syncthreads();
    if (tid == 0) {
        const float SC = (float)(1.0 / 54212400.0);  // 1/(4*370*370*99)
        atomicAdd(out, (wred[0] + wred[1] + wred[2] + wred[3]) * SC);
    }
}

extern "C" void kernel_launch(void* const* d_in, const int* in_sizes, int n_in,
                              void* d_out, int out_size, void* d_ws, size_t ws_size,
                              hipStream_t stream)
{
    (void)in_sizes; (void)n_in; (void)out_size; (void)ws_size;
    const float* pred = (const float*)d_in[0];
    const float* gt   = (const float*)d_in[1];
    float* out = (float*)d_out;
    float* ws  = (float*)d_ws;

    hipMemsetAsync(d_out, 0, sizeof(float), stream);

    dim3 g2(NXT2 * NYT2, 4, 2);     // 96 tiles x 4 batch x 2 images = 768 = 3/CU exact
    mind_stage2<<<g2, 256, 0, stream>>>(pred, gt, ws);
    dim3 g3(NTILE * NTILE, 4, 2);   // 144 tiles x 4 batch x 2 shift-halves
    mind_stage3<<<g3, 256, 0, stream>>>(pred, gt, ws, out);
}